// Round 10
// baseline (804.401 us; speedup 1.0000x reference)
//
#include <hip/hip_runtime.h>
#include <hip/hip_cooperative_groups.h>
namespace cg = cooperative_groups;

#define NN    100000   // N_NODES
#define F     64       // feature dim (= hidden dim)
#define NBUCK 391      // ceil(NN/256) buckets of 256 nodes
#define CAPB  4096     // per-bucket edge capacity (mean 3197, 16-sigma margin)
#define TILE  4096     // edges per binpack tile
#define GRID  1024     // 4 blocks/CU on 256 CUs -- co-resident by construction
#define BS    512
#define NGU   (NN / 32)   // 3125 gemm/agg units of 32 rows

// workspace offsets (4-byte elements)
#define O_CURSOR 0          // int[391]
#define O_ROWPTR 512        // int[100000]  absolute index into srt
#define O_DEG    100864     // int[100000]
#define O_DIS    201216     // float[100000]
#define O_PACKED 301568     // uint[391*4096]
#define O_SRT    1903104    // int[391*4096 + 64]
#define O_AH     3504768    // uint[NN*32]: bf16-packed A rows (128 B/row)
#define O_HH     6704768    // uint[NN*32]: bf16-packed h rows (layer-1 output)

// ---- bf16 pack/unpack (RNE; values finite) --------------------------------
__device__ __forceinline__ unsigned bf_rne(float x) {
    unsigned u = __float_as_uint(x);
    return (u + 0x7FFFu + ((u >> 16) & 1u)) >> 16;
}
__device__ __forceinline__ unsigned pack2(float lo, float hi) {
    return bf_rne(lo) | (bf_rne(hi) << 16);
}
__device__ __forceinline__ float lo_f(unsigned u) { return __uint_as_float(u << 16); }
__device__ __forceinline__ float hi_f(unsigned u) { return __uint_as_float(u & 0xFFFF0000u); }

// ---- shared-memory union: one 30.9 KB block reused per phase ---------------
struct BpSmem {
    int hist[NBUCK], lofs[NBUCK], gbase[NBUCK], lcur[NBUCK];
    int wsum[8];
    unsigned stage[TILE];                     // 16 KB
    unsigned short sbuck[TILE];               // 8 KB
};                                            // 30864 B
struct NsSmem {
    int h[256], lcur[256], wsum[4];
    int stage[CAPB];                          // 16 KB
};                                            // 18448 B
union KSmem {
    BpSmem bp;
    NsSmem ns;
    float  wl[64 * 64];                       // 16 KB
};

// ---------------------------------------------------------------------------
// binpack body: tile counting-sort into 391 bucket-strided regions (one
// global atomic per bucket per tile at implicit base b*CAPB).
// packed = (src<<8) | (dst & 255). 512 threads.
// ---------------------------------------------------------------------------
__device__ __forceinline__ void binpack_body(const int* __restrict__ src,
                                             const int* __restrict__ dst, int E,
                                             int* __restrict__ cursor,
                                             unsigned* __restrict__ packed,
                                             int bid, BpSmem& sm) {
    int t  = threadIdx.x;
    int t0 = bid * TILE;
    int n  = min(TILE, E - t0);

    if (t < NBUCK) sm.hist[t] = 0;
    __syncthreads();
    for (int i = t; i < n; i += BS) atomicAdd(&sm.hist[dst[t0 + i] >> 8], 1);
    __syncthreads();
    int lane = t & 63, w = t >> 6;
    int v = (t < NBUCK) ? sm.hist[t] : 0;
    int s = v;
#pragma unroll
    for (int off = 1; off < 64; off <<= 1) {
        int u = __shfl_up(s, off, 64);
        if (lane >= off) s += u;
    }
    if (lane == 63) sm.wsum[w] = s;
    __syncthreads();
    if (t == 0) {
        int run = 0;
#pragma unroll
        for (int i = 0; i < 8; ++i) { int c = sm.wsum[i]; sm.wsum[i] = run; run += c; }
    }
    __syncthreads();
    if (t < NBUCK) {
        int ex = s - v + sm.wsum[w];
        sm.lofs[t] = ex;
        sm.lcur[t] = ex;
        sm.gbase[t] = t * CAPB + (v ? atomicAdd(&cursor[t], v) : 0);
    }
    __syncthreads();
    for (int i = t; i < n; i += BS) {
        int d = dst[t0 + i];
        int b = d >> 8;
        int p = atomicAdd(&sm.lcur[b], 1);
        sm.stage[p] = ((unsigned)src[t0 + i] << 8) | (unsigned)(d & 255);
        sm.sbuck[p] = (unsigned short)b;
    }
    __syncthreads();
    for (int i = t; i < n; i += BS) {
        int b = sm.sbuck[i];
        packed[sm.gbase[b] + (i - sm.lofs[b])] = sm.stage[i];
    }
}

// ---------------------------------------------------------------------------
// gemm body (f32 X): Ah = bf16(X @ W). VALU loop, x broadcast via readlane.
// 8 waves x 4 rows = 32 rows per unit. Even lanes pack adjacent-col pairs.
// ---------------------------------------------------------------------------
__device__ __forceinline__ void gemm_body(const float* __restrict__ X,
                                          const float* __restrict__ W,
                                          unsigned* __restrict__ Ah, int bid,
                                          float* wl) {
    int t = threadIdx.x;
    for (int i = t; i < 64 * 64; i += BS) wl[i] = W[i];
    __syncthreads();
    int lane = t & 63;
    int w    = t >> 6;
    float Wreg[64];
#pragma unroll
    for (int k = 0; k < 64; ++k) Wreg[k] = wl[k * 64 + lane];

    int row0 = bid * 32 + w * 4;
    const float* xp = X + (size_t)row0 * F;
    float xa = xp[lane];
    float xb = xp[64 + lane];
    float xc = xp[128 + lane];
    float xd = xp[192 + lane];
    float a0 = 0.f, a1 = 0.f, a2 = 0.f, a3 = 0.f;
#pragma unroll
    for (int k = 0; k < 64; ++k) {
        float wv = Wreg[k];
        a0 = fmaf(__uint_as_float(__builtin_amdgcn_readlane(__float_as_uint(xa), k)), wv, a0);
        a1 = fmaf(__uint_as_float(__builtin_amdgcn_readlane(__float_as_uint(xb), k)), wv, a1);
        a2 = fmaf(__uint_as_float(__builtin_amdgcn_readlane(__float_as_uint(xc), k)), wv, a2);
        a3 = fmaf(__uint_as_float(__builtin_amdgcn_readlane(__float_as_uint(xd), k)), wv, a3);
    }
    float p0 = __shfl_xor(a0, 1, 64);
    float p1 = __shfl_xor(a1, 1, 64);
    float p2 = __shfl_xor(a2, 1, 64);
    float p3 = __shfl_xor(a3, 1, 64);
    if (!(lane & 1)) {
        int c = lane >> 1;
        Ah[(size_t)(row0 + 0) * 32 + c] = pack2(a0, p0);
        Ah[(size_t)(row0 + 1) * 32 + c] = pack2(a1, p1);
        Ah[(size_t)(row0 + 2) * 32 + c] = pack2(a2, p2);
        Ah[(size_t)(row0 + 3) * 32 + c] = pack2(a3, p3);
    }
}

// ---------------------------------------------------------------------------
// gemm body (bf16-packed H): Ah = bf16(H @ W). readlane + lo/hi select.
// ---------------------------------------------------------------------------
__device__ __forceinline__ void gemm_h_body(const unsigned* __restrict__ Hh,
                                            const float* __restrict__ W,
                                            unsigned* __restrict__ Ah, int bid,
                                            float* wl) {
    int t = threadIdx.x;
    for (int i = t; i < 64 * 64; i += BS) wl[i] = W[i];
    __syncthreads();
    int lane = t & 63;
    int w    = t >> 6;
    float Wreg[64];
#pragma unroll
    for (int k = 0; k < 64; ++k) Wreg[k] = wl[k * 64 + lane];

    int row0 = bid * 32 + w * 4;
    int l = lane & 31, r = lane >> 5;
    unsigned pa = Hh[(size_t)(row0 + r) * 32 + l];        // rows 0,1
    unsigned pb = Hh[(size_t)(row0 + 2 + r) * 32 + l];    // rows 2,3
    float a0 = 0.f, a1 = 0.f, a2 = 0.f, a3 = 0.f;
#pragma unroll
    for (int k = 0; k < 64; ++k) {
        float wv = Wreg[k];
        unsigned q0 = __builtin_amdgcn_readlane(pa, k >> 1);
        unsigned q1 = __builtin_amdgcn_readlane(pa, 32 + (k >> 1));
        unsigned q2 = __builtin_amdgcn_readlane(pb, k >> 1);
        unsigned q3 = __builtin_amdgcn_readlane(pb, 32 + (k >> 1));
        float x0 = (k & 1) ? hi_f(q0) : lo_f(q0);
        float x1 = (k & 1) ? hi_f(q1) : lo_f(q1);
        float x2 = (k & 1) ? hi_f(q2) : lo_f(q2);
        float x3 = (k & 1) ? hi_f(q3) : lo_f(q3);
        a0 = fmaf(x0, wv, a0);
        a1 = fmaf(x1, wv, a1);
        a2 = fmaf(x2, wv, a2);
        a3 = fmaf(x3, wv, a3);
    }
    float p0 = __shfl_xor(a0, 1, 64);
    float p1 = __shfl_xor(a1, 1, 64);
    float p2 = __shfl_xor(a2, 1, 64);
    float p3 = __shfl_xor(a3, 1, 64);
    if (!(lane & 1)) {
        int c = lane >> 1;
        Ah[(size_t)(row0 + 0) * 32 + c] = pack2(a0, p0);
        Ah[(size_t)(row0 + 1) * 32 + c] = pack2(a1, p1);
        Ah[(size_t)(row0 + 2) * 32 + c] = pack2(a2, p2);
        Ah[(size_t)(row0 + 3) * 32 + c] = pack2(a3, p3);
    }
}

// ---------------------------------------------------------------------------
// node_sort body: per-bucket LDS counting sort; emits row_ptr, deg, dis.
// ---------------------------------------------------------------------------
__device__ __forceinline__ void node_sort_body(const unsigned* __restrict__ packed,
                                               const int* __restrict__ cursor,
                                               int* __restrict__ row_ptr,
                                               int* __restrict__ deg,
                                               float* __restrict__ dis,
                                               int* __restrict__ srt,
                                               int b, NsSmem& sm) {
    int t = threadIdx.x;
    int nbase = b << 8;
    int nloc = min(256, NN - nbase);
    int beg = b * CAPB;
    int n = cursor[b];

    if (t < 256) sm.h[t] = 0;
    __syncthreads();
    for (int i = t; i < n; i += BS)
        atomicAdd(&sm.h[packed[beg + i] & 255u], 1);
    __syncthreads();
    int lane = t & 63, w = t >> 6;
    int v = 0, s = 0;
    if (t < 256) { v = sm.h[t]; s = v; }
#pragma unroll
    for (int off = 1; off < 64; off <<= 1) {
        int u = __shfl_up(s, off, 64);
        if (lane >= off) s += u;
    }
    if (t < 256 && lane == 63) sm.wsum[w] = s;
    __syncthreads();
    if (t == 0) {
        int run = 0;
#pragma unroll
        for (int i = 0; i < 4; ++i) { int c = sm.wsum[i]; sm.wsum[i] = run; run += c; }
    }
    __syncthreads();
    if (t < 256) {
        int e0 = s - v + sm.wsum[w];
        sm.lcur[t] = e0;
        if (t < nloc) {
            row_ptr[nbase + t] = beg + e0;
            deg[nbase + t]     = v;
            dis[nbase + t]     = rsqrtf((float)v + 1.0f);   // +1 = self-loop
        }
    }
    __syncthreads();
    for (int i = t; i < n; i += BS) {
        unsigned p = packed[beg + i];
        int pos = atomicAdd(&sm.lcur[p & 255u], 1);
        sm.stage[pos] = (int)(p >> 8);
    }
    __syncthreads();
    for (int i = t; i < n; i += BS) srt[beg + i] = sm.stage[i];
}

// ---------------------------------------------------------------------------
// agg body: gather over bf16 A with per-edge dis[s] + fused bias.
// 512 threads -> 32 nodes per unit, 16 lanes/node (4 bf16 cols/lane).
// MODE 1: ReLU + bf16-packed h out.  MODE 0: float4 out.
// ---------------------------------------------------------------------------
template <int MODE>
__device__ __forceinline__ void agg_body(const uint2* __restrict__ Ah2,
                                         const int* __restrict__ row_ptr,
                                         const int* __restrict__ deg,
                                         const int* __restrict__ srt,
                                         const float* __restrict__ dis,
                                         const float* __restrict__ bias,
                                         void* __restrict__ outp, int g) {
    int sub  = threadIdx.x & 15;
    int node = g * 32 + (threadIdx.x >> 4);
    int beg = row_ptr[node];
    int end = beg + deg[node];
    float di = dis[node];
    uint2 su = Ah2[(size_t)node * 16 + sub];
    float4 acc;
    acc.x = di * lo_f(su.x);
    acc.y = di * hi_f(su.x);
    acc.z = di * lo_f(su.y);
    acc.w = di * hi_f(su.y);
    int j = beg;
    for (; j + 4 <= end; j += 4) {
        int s0 = srt[j], s1 = srt[j + 1], s2 = srt[j + 2], s3 = srt[j + 3];
        float d0 = dis[s0], d1 = dis[s1], d2 = dis[s2], d3 = dis[s3];
        uint2 g0 = Ah2[(size_t)s0 * 16 + sub];
        uint2 g1 = Ah2[(size_t)s1 * 16 + sub];
        uint2 g2 = Ah2[(size_t)s2 * 16 + sub];
        uint2 g3 = Ah2[(size_t)s3 * 16 + sub];
        acc.x = fmaf(d0, lo_f(g0.x), fmaf(d1, lo_f(g1.x), fmaf(d2, lo_f(g2.x), fmaf(d3, lo_f(g3.x), acc.x))));
        acc.y = fmaf(d0, hi_f(g0.x), fmaf(d1, hi_f(g1.x), fmaf(d2, hi_f(g2.x), fmaf(d3, hi_f(g3.x), acc.y))));
        acc.z = fmaf(d0, lo_f(g0.y), fmaf(d1, lo_f(g1.y), fmaf(d2, lo_f(g2.y), fmaf(d3, lo_f(g3.y), acc.z))));
        acc.w = fmaf(d0, hi_f(g0.y), fmaf(d1, hi_f(g1.y), fmaf(d2, hi_f(g2.y), fmaf(d3, hi_f(g3.y), acc.w))));
    }
    for (; j < end; ++j) {
        int s0 = srt[j];
        float d0 = dis[s0];
        uint2 g0 = Ah2[(size_t)s0 * 16 + sub];
        acc.x = fmaf(d0, lo_f(g0.x), acc.x);
        acc.y = fmaf(d0, hi_f(g0.x), acc.y);
        acc.z = fmaf(d0, lo_f(g0.y), acc.z);
        acc.w = fmaf(d0, hi_f(g0.y), acc.w);
    }
    float4 bb = ((const float4*)bias)[sub];
    float4 o;
    o.x = fmaf(di, acc.x, bb.x);
    o.y = fmaf(di, acc.y, bb.y);
    o.z = fmaf(di, acc.z, bb.z);
    o.w = fmaf(di, acc.w, bb.w);
    if (MODE == 1) {
        o.x = fmaxf(o.x, 0.f); o.y = fmaxf(o.y, 0.f);
        o.z = fmaxf(o.z, 0.f); o.w = fmaxf(o.w, 0.f);
        uint2 pk;
        pk.x = pack2(o.x, o.y);
        pk.y = pack2(o.z, o.w);
        ((uint2*)outp)[(size_t)node * 16 + sub] = pk;
    } else {
        ((float4*)outp)[(size_t)node * 16 + sub] = o;
    }
}

// ---------------------------------------------------------------------------
// THE fused cooperative kernel: all 6 phases, grid.sync() between.
// GRID=1024 blocks x 512 thr = exactly 4 blocks/CU co-resident.
// ---------------------------------------------------------------------------
__global__ __launch_bounds__(BS, 8) void gcn_fused(
        const int* src, const int* dst, int E, int nbp,
        int* cursor, unsigned* packed, int* row_ptr, int* deg, float* dis,
        int* srt, unsigned* Ah, unsigned* Hh,
        const float* x, const float* W1, const float* b1,
        const float* W2, const float* b2, float* out) {
    cg::grid_group gg = cg::this_grid();
    __shared__ KSmem sm;
    int bid = blockIdx.x;
    int t   = threadIdx.x;

    // phase 0: zero cursor
    if (bid == 0 && t < NBUCK) cursor[t] = 0;
    gg.sync();

    // phase 1: binpack tiles [0,nbp) then gemm1 units [nbp, nbp+NGU),
    // one grid-stride loop; binpack items come first so all tiles start at t=0.
    for (int wk = bid; wk < nbp + NGU; wk += GRID) {
        if (wk < nbp) binpack_body(src, dst, E, cursor, packed, wk, sm.bp);
        else          gemm_body(x, W1, Ah, wk - nbp, sm.wl);
        __syncthreads();
    }
    gg.sync();

    // phase 2: node_sort (391 buckets; blocks >= NBUCK idle)
    if (bid < NBUCK) node_sort_body(packed, cursor, row_ptr, deg, dis, srt, bid, sm.ns);
    gg.sync();

    // phase 3: layer-1 aggregate -> bf16 h
    for (int g = bid; g < NGU; g += GRID)
        agg_body<1>((const uint2*)Ah, row_ptr, deg, srt, dis, b1, Hh, g);
    gg.sync();

    // phase 4: layer-2 gemm (bf16 h) -> bf16 Ah
    for (int g = bid; g < NGU; g += GRID) {
        gemm_h_body(Hh, W2, Ah, g, sm.wl);
        __syncthreads();
    }
    gg.sync();

    // phase 5: layer-2 aggregate -> f32 out
    for (int g = bid; g < NGU; g += GRID)
        agg_body<0>((const uint2*)Ah, row_ptr, deg, srt, dis, b2, out, g);
}

// ---------------- fallback path (6 dispatches; proven R9 structure) ---------
__global__ __launch_bounds__(BS) void fb_pre_gemm1(const int* src, const int* dst,
                                                   int E, int nbp, int* cursor,
                                                   unsigned* packed, const float* x,
                                                   const float* W1, unsigned* Ah) {
    __shared__ KSmem sm;
    if ((int)blockIdx.x < nbp)
        binpack_body(src, dst, E, cursor, packed, blockIdx.x, sm.bp);
    else
        gemm_body(x, W1, Ah, blockIdx.x - nbp, sm.wl);
}
__global__ __launch_bounds__(BS) void fb_node_sort(const unsigned* packed,
                                                   const int* cursor, int* row_ptr,
                                                   int* deg, float* dis, int* srt) {
    __shared__ NsSmem sm;
    node_sort_body(packed, cursor, row_ptr, deg, dis, srt, blockIdx.x, sm);
}
template <int MODE>
__global__ __launch_bounds__(BS) void fb_agg(const uint2* Ah2, const int* row_ptr,
                                             const int* deg, const int* srt,
                                             const float* dis, const float* bias,
                                             void* outp) {
    agg_body<MODE>(Ah2, row_ptr, deg, srt, dis, bias, outp, blockIdx.x);
}
__global__ __launch_bounds__(BS) void fb_gemm2h(const unsigned* Hh, const float* W,
                                                unsigned* Ah) {
    __shared__ float wl[64 * 64];
    gemm_h_body(Hh, W, Ah, blockIdx.x, wl);
}

extern "C" void kernel_launch(void* const* d_in, const int* in_sizes, int n_in,
                              void* d_out, int out_size, void* d_ws, size_t ws_size,
                              hipStream_t stream) {
    const float* x  = (const float*)d_in[0];
    const int*   ei = (const int*)d_in[1];   // [2,E]: src = ei[0:E], dst = ei[E:2E]
    const float* W1 = (const float*)d_in[2];
    const float* b1 = (const float*)d_in[3];
    const float* W2 = (const float*)d_in[4];
    const float* b2 = (const float*)d_in[5];
    float* out = (float*)d_out;
    int E = in_sizes[1] / 2;
    const int* src = ei;
    const int* dst = ei + E;

    int*      ws_i    = (int*)d_ws;
    int*      cursor  = ws_i + O_CURSOR;
    int*      row_ptr = ws_i + O_ROWPTR;
    int*      deg     = ws_i + O_DEG;
    float*    dis     = (float*)(ws_i + O_DIS);
    unsigned* packed  = (unsigned*)(ws_i + O_PACKED);
    int*      srt     = ws_i + O_SRT;
    unsigned* Ah      = (unsigned*)(ws_i + O_AH);
    unsigned* Hh      = (unsigned*)(ws_i + O_HH);

    int nbp = (E + TILE - 1) / TILE;

    void* kargs[] = {
        (void*)&src, (void*)&dst, (void*)&E, (void*)&nbp,
        (void*)&cursor, (void*)&packed, (void*)&row_ptr, (void*)&deg,
        (void*)&dis, (void*)&srt, (void*)&Ah, (void*)&Hh,
        (void*)&x, (void*)&W1, (void*)&b1, (void*)&W2, (void*)&b2, (void*)&out
    };
    hipError_t err = hipLaunchCooperativeKernel((void*)gcn_fused, dim3(GRID),
                                                dim3(BS), kargs, 0, stream);
    if (err != hipSuccess) {
        // deterministic fallback: R9 6-dispatch pipeline
        hipMemsetAsync(cursor, 0, NBUCK * sizeof(int), stream);
        fb_pre_gemm1<<<nbp + NGU, BS, 0, stream>>>(src, dst, E, nbp, cursor, packed,
                                                   x, W1, Ah);
        fb_node_sort<<<NBUCK, BS, 0, stream>>>(packed, cursor, row_ptr, deg, dis, srt);
        fb_agg<1><<<NGU, BS, 0, stream>>>((const uint2*)Ah, row_ptr, deg, srt, dis,
                                          b1, Hh);
        fb_gemm2h<<<NGU, BS, 0, stream>>>(Hh, W2, Ah);
        fb_agg<0><<<NGU, BS, 0, stream>>>((const uint2*)Ah, row_ptr, deg, srt, dis,
                                          b2, out);
    }
}